// Round 9
// baseline (614.740 us; speedup 1.0000x reference)
//
#include <hip/hip_runtime.h>
#include <hip/hip_cooperative_groups.h>

// GCN encoder: 2x (dense transform -> symmetric-normalized neighbor aggregation)
// R3: bf16x3 split MFMA GEMMs (no fp32 MFMA on CDNA4), W pre-swizzled.
// R4: aggregation gather tables bf16 -> halved beyond-L2 gather traffic.
// R5 FAILED: cross-thread fence race in ticket scan -> OOB -> abort.
// R6/R7: race-free fusions + atomic-free bucketed CSR build; 175.5 us,
//        ~8-10 us per kernel boundary across 7 dispatches.
// R8 FAILED: hipLaunchCooperativeKernel returned an error (output = clean
//        zeros, the launch-never-ran signature); grid=1024 likely exceeded
//        the runtime's cooperative capacity check. Return code was unchecked.
// R9: (a) cooperative grid sized from hipOccupancyMaxActiveBlocksPerMultiprocessor
//        x CU count (host queries; capture-safe); all phases gridDim.x-strided
//        so any grid size is correct. (b) launch return code checked; on error
//        fall back to the proven R7 7-dispatch path (same device-function
//        bodies). Deterministic -> same work every call.

namespace cg = cooperative_groups;

typedef __attribute__((ext_vector_type(8))) short short8;
typedef __attribute__((ext_vector_type(4))) float float4v;

constexpr int PB = 128;  // partition blocks (histogram/scatter chunks)

static __device__ __forceinline__ ushort f2bf(float f) {
  union { float f; unsigned u; } c; c.f = f;
  unsigned u = c.u;
  return (ushort)((u + 0x7fffu + ((u >> 16) & 1u)) >> 16);  // RNE
}
static __device__ __forceinline__ float bf2f(ushort h) {
  union { unsigned u; float f; } c; c.u = ((unsigned)h) << 16;
  return c.f;
}
static __device__ __forceinline__ float bfhi(unsigned packed) {
  union { unsigned u; float f; } c; c.u = packed & 0xffff0000u;
  return c.f;
}
static __device__ __forceinline__ float bflo(unsigned packed) {
  union { unsigned u; float f; } c; c.u = packed << 16;
  return c.f;
}

struct MegaParams {
  const float* x;
  const int* src;
  const int* dst;
  const float* W1;
  const float* b1;
  const float* W2;
  const float* b2;
  int N, E, NBK, EPB, GB, NAGG;
  int* cnt_mat;
  int* btot;
  unsigned* part;
  int* row_ptr;
  float* dinv;
  int* col;
  ushort* h;
  ushort* h1hi;
  ushort* h1lo;
  ushort* h2;
  ushort* w1hi;
  ushort* w1lo;
  ushort* w2hi;
  ushort* w2lo;
  float* out;
};

// W swizzle: one 16x32 B-fragment tile (64 lanes).
// Layout [ktile][ntile][lane][j]: B[k=(lane>>4)*8+j][n=lane&15]
static __device__ __forceinline__ void wswz_tile(const float* __restrict__ W,
                                                 ushort* __restrict__ whi,
                                                 ushort* __restrict__ wlo,
                                                 int M, int tile, int lane) {
  int ntiles = M >> 4;
  int kt = tile / ntiles, nt = tile % ntiles;
  int colg = nt * 16 + (lane & 15);
  int krow = kt * 32 + (lane >> 4) * 8;
  size_t o = ((size_t)tile * 64 + lane) * 8;
#pragma unroll
  for (int j = 0; j < 8; j++) {
    float v = W[(size_t)(krow + j) * M + colg];
    ushort h = f2bf(v);
    whi[o + j] = h;
    wlo[o + j] = f2bf(v - bf2f(h));
  }
}

// Exclusive scan of m (<512) global ints into LDS base[512]; base[idx>=m] = total.
static __device__ __forceinline__ void lds_scan512(const int* __restrict__ g, int m,
                                                   int* __restrict__ base,
                                                   int* __restrict__ buf) {
  int t = threadIdx.x;
  int carry = 0;
  for (int b0 = 0; b0 < 512; b0 += 256) {
    int idx = b0 + t;
    int v = (idx < m) ? g[idx] : 0;
    buf[t] = v;
    __syncthreads();
    for (int off = 1; off < 256; off <<= 1) {
      int add = (t >= off) ? buf[t - off] : 0;
      __syncthreads();
      buf[t] += add;
      __syncthreads();
    }
    base[idx] = carry + buf[t] - v;
    carry += buf[255];
    __syncthreads();
  }
}

// ---- Phase 1 body: bucket histogram (bid<PB) or W swizzle (bid in [PB,PB+12)) ----
static __device__ void phase1_body(int bid, const MegaParams& P, int* smem) {
  int t = threadIdx.x;
  if (bid >= PB) {
    int tile = (bid - PB) * 4 + (t >> 6);
    int lane = t & 63;
    if (tile < 32) wswz_tile(P.W1, P.w1hi, P.w1lo, 128, tile, lane);
    else           wswz_tile(P.W2, P.w2hi, P.w2lo, 64, tile - 32, lane);
    return;
  }
  int* hist = smem;
  for (int k = t; k < P.NBK; k += 256) hist[k] = 0;
  __syncthreads();
  int start = bid * P.EPB;
  int stop = min(P.E, start + P.EPB);
  for (int e = start + t * 4; e < stop; e += 1024) {
    if (e + 4 <= stop) {
      int4 d = *(const int4*)(P.dst + e);
      atomicAdd(&hist[d.x >> 7], 1);
      atomicAdd(&hist[d.y >> 7], 1);
      atomicAdd(&hist[d.z >> 7], 1);
      atomicAdd(&hist[d.w >> 7], 1);
    } else {
      for (int j = e; j < stop; j++) atomicAdd(&hist[P.dst[j] >> 7], 1);
    }
  }
  __syncthreads();
  for (int k = t; k < P.NBK; k += 256) P.cnt_mat[k * PB + bid] = hist[k];
}

// ---- Phase 2 scan body: per-bucket exclusive scan of cnt_mat row ----
static __device__ void phase2_scan(int bid, const MegaParams& P, int* smem) {
  int t = threadIdx.x;
  int* buf = smem;
  int v = (t < PB) ? P.cnt_mat[bid * PB + t] : 0;
  buf[t] = v;
  __syncthreads();
#pragma unroll
  for (int off = 1; off < 256; off <<= 1) {
    int add = (t >= off) ? buf[t - off] : 0;
    __syncthreads();
    buf[t] += add;
    __syncthreads();
  }
  if (t < PB) P.cnt_mat[bid * PB + t] = buf[t] - v;
  if (t == 255) P.btot[bid] = buf[255];
}

// ---- gemm1 block: C[64 rows, 128] = A @ W1, fp32 A split to bf16 hi/lo ----
static __device__ void gemm1_block(int gb, const MegaParams& P) {
  constexpr int K = 128, M = 128, NT = M / 16;
  int t = threadIdx.x;
  int lane = t & 63;
  int wv = t >> 6;
  int quad = lane >> 4, lo16 = lane & 15;
  int rowbase = gb * 64 + wv * 16;
  int arow = rowbase + lo16;
  bool arow_ok = arow < P.N;
  float4v acc[NT];
#pragma unroll
  for (int nt = 0; nt < NT; nt++) acc[nt] = (float4v){0.f, 0.f, 0.f, 0.f};
  for (int kt = 0; kt < 4; kt++) {
    short8 ahi, alo;
    float av[8];
    if (arow_ok) {
      const float* ap = P.x + (size_t)arow * K + kt * 32 + quad * 8;
      float4 a0 = *(const float4*)ap;
      float4 a1 = *(const float4*)(ap + 4);
      av[0] = a0.x; av[1] = a0.y; av[2] = a0.z; av[3] = a0.w;
      av[4] = a1.x; av[5] = a1.y; av[6] = a1.z; av[7] = a1.w;
    } else {
#pragma unroll
      for (int j = 0; j < 8; j++) av[j] = 0.f;
    }
#pragma unroll
    for (int j = 0; j < 8; j++) {
      ushort hh = f2bf(av[j]);
      ahi[j] = (short)hh;
      alo[j] = (short)f2bf(av[j] - bf2f(hh));
    }
    const ushort* ph = P.w1hi + ((size_t)(kt * NT) * 64 + lane) * 8;
    const ushort* pl = P.w1lo + ((size_t)(kt * NT) * 64 + lane) * 8;
#pragma unroll
    for (int nt = 0; nt < NT; nt++) {
      short8 bhi = *(const short8*)(ph + nt * 512);
      short8 blo = *(const short8*)(pl + nt * 512);
      acc[nt] = __builtin_amdgcn_mfma_f32_16x16x32_bf16(ahi, bhi, acc[nt], 0, 0, 0);
      acc[nt] = __builtin_amdgcn_mfma_f32_16x16x32_bf16(alo, bhi, acc[nt], 0, 0, 0);
      acc[nt] = __builtin_amdgcn_mfma_f32_16x16x32_bf16(ahi, blo, acc[nt], 0, 0, 0);
    }
  }
  // D layout (m89-verified): col = lane&15, row = quad*4 + reg
#pragma unroll
  for (int nt = 0; nt < NT; nt++) {
#pragma unroll
    for (int r = 0; r < 4; r++) {
      int row = rowbase + quad * 4 + r;
      if (row < P.N) P.h[(size_t)row * M + nt * 16 + lo16] = f2bf(acc[nt][r]);
    }
  }
}

// ---- Phase 3 body: partition scatter (LDS cursors, disjoint output ranges) ----
static __device__ void phase3_body(int bid, const MegaParams& P, int* smem) {
  int t = threadIdx.x;
  int* buf = smem;           // 256
  int* base = smem + 256;    // 512
  int* cur = smem + 768;     // 512
  lds_scan512(P.btot, P.NBK, base, buf);
  for (int k = t; k < P.NBK; k += 256) cur[k] = base[k] + P.cnt_mat[k * PB + bid];
  __syncthreads();
  int start = bid * P.EPB, stop = min(P.E, start + P.EPB);
  for (int e = start + t * 4; e < stop; e += 1024) {
    if (e + 4 <= stop) {
      int4 s = *(const int4*)(P.src + e);
      int4 d = *(const int4*)(P.dst + e);
      int p;
      p = atomicAdd(&cur[d.x >> 7], 1); P.part[p] = (unsigned)s.x | ((unsigned)(d.x & 127) << 25);
      p = atomicAdd(&cur[d.y >> 7], 1); P.part[p] = (unsigned)s.y | ((unsigned)(d.y & 127) << 25);
      p = atomicAdd(&cur[d.z >> 7], 1); P.part[p] = (unsigned)s.z | ((unsigned)(d.z & 127) << 25);
      p = atomicAdd(&cur[d.w >> 7], 1); P.part[p] = (unsigned)s.w | ((unsigned)(d.w & 127) << 25);
    } else {
      for (int j = e; j < stop; j++) {
        int p2 = atomicAdd(&cur[P.dst[j] >> 7], 1);
        P.part[p2] = (unsigned)P.src[j] | ((unsigned)(P.dst[j] & 127) << 25);
      }
    }
  }
}

// ---- Phase 4 body: per-bucket local CSR (LDS count/scan/place) ----
static __device__ void phase4_body(int bid, const MegaParams& P, int* smem) {
  int t = threadIdx.x;
  int* buf = smem;            // 256
  int* base = smem + 256;     // 512
  int* cnt = smem + 768;      // 128
  int* cur = smem + 896;      // 128
  lds_scan512(P.btot, P.NBK, base, buf);
  int beg = base[bid], end = base[bid + 1];
  if (t < 128) cnt[t] = 0;
  __syncthreads();
  for (int e = beg + t; e < end; e += 256) atomicAdd(&cnt[P.part[e] >> 25], 1);
  __syncthreads();
  int v = (t < 128) ? cnt[t] : 0;
  buf[t] = v;
  __syncthreads();
#pragma unroll
  for (int off = 1; off < 256; off <<= 1) {
    int add = (t >= off) ? buf[t - off] : 0;
    __syncthreads();
    buf[t] += add;
    __syncthreads();
  }
  if (t < 128) {
    int excl = buf[t] - v;
    cur[t] = beg + excl;
    int node = bid * 128 + t;
    if (node < P.N) {
      P.row_ptr[node] = beg + excl;
      P.dinv[node] = rsqrtf((float)(v + 1));  // +1 self loop
    }
  }
  if (bid == 0 && t == 0) P.row_ptr[P.N] = P.E;
  __syncthreads();
  for (int e = beg + t; e < end; e += 256) {
    unsigned p = P.part[e];
    int pos = atomicAdd(&cur[p >> 25], 1);
    P.col[pos] = (int)(p & 0x01FFFFFFu);
  }
}

// ---- gemm2 block: PRESPLIT bf16 hi/lo in, bf16 out, M=64 ----
static __device__ void gemm2_block(int gb, const MegaParams& P) {
  constexpr int K = 128, M = 64, NT = M / 16;
  int t = threadIdx.x;
  int lane = t & 63;
  int wv = t >> 6;
  int quad = lane >> 4, lo16 = lane & 15;
  int rowbase = gb * 64 + wv * 16;
  int arow = rowbase + lo16;
  bool arow_ok = arow < P.N;
  float4v acc[NT];
#pragma unroll
  for (int nt = 0; nt < NT; nt++) acc[nt] = (float4v){0.f, 0.f, 0.f, 0.f};
  for (int kt = 0; kt < 4; kt++) {
    short8 ahi, alo;
    if (arow_ok) {
      size_t ao = (size_t)arow * K + kt * 32 + quad * 8;
      ahi = *(const short8*)(P.h1hi + ao);
      alo = *(const short8*)(P.h1lo + ao);
    } else {
      ahi = (short8)0; alo = (short8)0;
    }
    const ushort* ph = P.w2hi + ((size_t)(kt * NT) * 64 + lane) * 8;
    const ushort* pl = P.w2lo + ((size_t)(kt * NT) * 64 + lane) * 8;
#pragma unroll
    for (int nt = 0; nt < NT; nt++) {
      short8 bhi = *(const short8*)(ph + nt * 512);
      short8 blo = *(const short8*)(pl + nt * 512);
      acc[nt] = __builtin_amdgcn_mfma_f32_16x16x32_bf16(ahi, bhi, acc[nt], 0, 0, 0);
      acc[nt] = __builtin_amdgcn_mfma_f32_16x16x32_bf16(alo, bhi, acc[nt], 0, 0, 0);
      acc[nt] = __builtin_amdgcn_mfma_f32_16x16x32_bf16(ahi, blo, acc[nt], 0, 0, 0);
    }
  }
#pragma unroll
  for (int nt = 0; nt < NT; nt++) {
#pragma unroll
    for (int r = 0; r < 4; r++) {
      int row = rowbase + quad * 4 + r;
      if (row < P.N) P.h2[(size_t)row * M + nt * 16 + lo16] = f2bf(acc[nt][r]);
    }
  }
}

// ---- aggregation: one wave per node, channels across lanes ----
template <int C, bool RELU, bool SPLIT>
static __device__ void agg_block(int vb, const MegaParams& P,
                                 const ushort* __restrict__ Hb,
                                 const float* __restrict__ bias,
                                 float* __restrict__ out,
                                 ushort* __restrict__ outhi,
                                 ushort* __restrict__ outlo) {
  constexpr int VPL = C / 64;  // 2 (C=128) or 1 (C=64)
  int lane = threadIdx.x & 63;
  int v = vb * 4 + (threadIdx.x >> 6);
  if (v >= P.N) return;  // per-wave guard; no barriers below
  float dv = P.dinv[v];
  float acc0 = 0.f, acc1 = 0.f;
  auto loadp = [&](int s) -> unsigned {
    if (VPL == 2) return *(const unsigned*)(Hb + (size_t)s * C + lane * 2);
    else          return (unsigned)Hb[(size_t)s * C + lane];
  };
  {
    unsigned u = loadp(v);  // self loop (weight dv)
    if (VPL == 2) { acc0 = dv * bflo(u); acc1 = dv * bfhi(u); }
    else          { acc0 = dv * bf2f((ushort)u); }
  }
  int beg = P.row_ptr[v], end = P.row_ptr[v + 1];
  for (int base = beg; base < end; base += 64) {
    int m = end - base;
    if (m > 64) m = 64;
    int sl = 0;
    float wl = 0.f;
    if (lane < m) {
      sl = P.col[base + lane];
      wl = P.dinv[sl];
    }
    int j = 0;
    for (; j + 8 <= m; j += 8) {
      int s[8]; float wq[8]; unsigned u[8];
#pragma unroll
      for (int q = 0; q < 8; q++) { s[q] = __shfl(sl, j + q); wq[q] = __shfl(wl, j + q); }
#pragma unroll
      for (int q = 0; q < 8; q++) u[q] = loadp(s[q]);
#pragma unroll
      for (int q = 0; q < 8; q++) {
        if (VPL == 2) {
          acc0 = fmaf(wq[q], bflo(u[q]), acc0);
          acc1 = fmaf(wq[q], bfhi(u[q]), acc1);
        } else {
          acc0 = fmaf(wq[q], bf2f((ushort)u[q]), acc0);
        }
      }
    }
    for (; j + 4 <= m; j += 4) {
      int s[4]; float wq[4]; unsigned u[4];
#pragma unroll
      for (int q = 0; q < 4; q++) { s[q] = __shfl(sl, j + q); wq[q] = __shfl(wl, j + q); }
#pragma unroll
      for (int q = 0; q < 4; q++) u[q] = loadp(s[q]);
#pragma unroll
      for (int q = 0; q < 4; q++) {
        if (VPL == 2) {
          acc0 = fmaf(wq[q], bflo(u[q]), acc0);
          acc1 = fmaf(wq[q], bfhi(u[q]), acc1);
        } else {
          acc0 = fmaf(wq[q], bf2f((ushort)u[q]), acc0);
        }
      }
    }
    for (; j < m; j++) {
      int s = __shfl(sl, j);
      float wv = __shfl(wl, j);
      unsigned u = loadp(s);
      if (VPL == 2) {
        acc0 = fmaf(wv, bflo(u), acc0);
        acc1 = fmaf(wv, bfhi(u), acc1);
      } else {
        acc0 = fmaf(wv, bf2f((ushort)u), acc0);
      }
    }
  }
  float r0 = fmaf(dv, acc0, bias[lane * VPL + 0]);
  if (RELU) r0 = fmaxf(r0, 0.f);
  if (VPL == 2) {
    float r1 = fmaf(dv, acc1, bias[lane * VPL + 1]);
    if (RELU) r1 = fmaxf(r1, 0.f);
    if (SPLIT) {
      ushort h0 = f2bf(r0), h1 = f2bf(r1);
      ushort l0 = f2bf(r0 - bf2f(h0)), l1 = f2bf(r1 - bf2f(h1));
      ((unsigned*)outhi)[(size_t)v * (C / 2) + lane] = (unsigned)h0 | ((unsigned)h1 << 16);
      ((unsigned*)outlo)[(size_t)v * (C / 2) + lane] = (unsigned)l0 | ((unsigned)l1 << 16);
    } else {
      *(float2*)&out[(size_t)v * C + lane * 2] = make_float2(r0, r1);
    }
  } else {
    if (SPLIT) {
      ushort h0 = f2bf(r0);
      outhi[(size_t)v * C + lane] = h0;
      outlo[(size_t)v * C + lane] = f2bf(r0 - bf2f(h0));
    } else {
      out[(size_t)v * C + lane] = r0;
    }
  }
}

// ---- single cooperative kernel; every phase is gridDim.x-strided ------
__global__ __launch_bounds__(256, 4) void k_mega(MegaParams P) {
  cg::grid_group grid = cg::this_grid();
  __shared__ int smem[1280];  // 5 KB arena, aliased per phase
  int bid = blockIdx.x;
  int stride = gridDim.x;

  for (int vb = bid; vb < PB + 12; vb += stride) { phase1_body(vb, P, smem); __syncthreads(); }
  grid.sync();
  for (int vb = bid; vb < P.NBK + P.GB; vb += stride) {
    if (vb < P.NBK) { phase2_scan(vb, P, smem); __syncthreads(); }
    else            gemm1_block(vb - P.NBK, P);
  }
  grid.sync();
  for (int vb = bid; vb < PB; vb += stride) { phase3_body(vb, P, smem); __syncthreads(); }
  grid.sync();
  for (int vb = bid; vb < P.NBK; vb += stride) { phase4_body(vb, P, smem); __syncthreads(); }
  grid.sync();
  for (int vb = bid; vb < P.NAGG; vb += stride)
    agg_block<128, true, true>(vb, P, P.h, P.b1, nullptr, P.h1hi, P.h1lo);
  grid.sync();
  for (int vb = bid; vb < P.GB; vb += stride) gemm2_block(vb, P);
  grid.sync();
  for (int vb = bid; vb < P.NAGG; vb += stride)
    agg_block<64, false, false>(vb, P, P.h2, P.b2, P.out, nullptr, nullptr);
}

// ---- fallback wrappers: the proven R7 7-dispatch path ------------------
__global__ __launch_bounds__(256) void k_f1(MegaParams P) {
  __shared__ int smem[1280];
  phase1_body(blockIdx.x, P, smem);
}
__global__ __launch_bounds__(256) void k_f2(MegaParams P) {
  __shared__ int smem[1280];
  int bid = blockIdx.x;
  if (bid < P.NBK) phase2_scan(bid, P, smem);
  else             gemm1_block(bid - P.NBK, P);
}
__global__ __launch_bounds__(256) void k_f3(MegaParams P) {
  __shared__ int smem[1280];
  phase3_body(blockIdx.x, P, smem);
}
__global__ __launch_bounds__(256) void k_f4(MegaParams P) {
  __shared__ int smem[1280];
  phase4_body(blockIdx.x, P, smem);
}
__global__ __launch_bounds__(256) void k_f5(MegaParams P) {
  agg_block<128, true, true>(blockIdx.x, P, P.h, P.b1, nullptr, P.h1hi, P.h1lo);
}
__global__ __launch_bounds__(256) void k_f6(MegaParams P) {
  gemm2_block(blockIdx.x, P);
}
__global__ __launch_bounds__(256) void k_f7(MegaParams P) {
  agg_block<64, false, false>(blockIdx.x, P, P.h2, P.b2, P.out, nullptr, nullptr);
}

extern "C" void kernel_launch(void* const* d_in, const int* in_sizes, int n_in,
                              void* d_out, int out_size, void* d_ws, size_t ws_size,
                              hipStream_t stream) {
  MegaParams P;
  P.x  = (const float*)d_in[0];
  const int* ei = (const int*)d_in[1];
  P.W1 = (const float*)d_in[2];
  P.b1 = (const float*)d_in[3];
  P.W2 = (const float*)d_in[4];
  P.b2 = (const float*)d_in[5];
  P.N = in_sizes[0] / 128;
  P.E = in_sizes[1] / 2;
  P.src = ei;
  P.dst = ei + P.E;
  P.NBK = (P.N + 127) / 128;                   // 391; must be <= 512
  P.EPB = ((P.E + PB - 1) / PB + 3) & ~3;      // edges per partition block, x4
  P.GB = (P.N + 63) / 64;                      // 782
  P.NAGG = (P.N + 3) / 4;                      // 12500

  auto al = [](size_t v) { return (v + 255) & ~(size_t)255; };
  char* w = (char*)d_ws;
  P.cnt_mat = (int*)w;      w += al((size_t)P.NBK * PB * 4);
  P.btot    = (int*)w;      w += al((size_t)P.NBK * 4);
  P.part    = (unsigned*)w; w += al((size_t)P.E * 4);
  P.row_ptr = (int*)w;      w += al((size_t)(P.N + 1) * 4);
  P.dinv    = (float*)w;    w += al((size_t)P.N * 4);
  P.col     = (int*)w;      w += al((size_t)P.E * 4);
  P.h       = (ushort*)w;   w += al((size_t)P.N * 128 * 2);
  P.h1hi    = (ushort*)w;   w += al((size_t)P.N * 128 * 2);
  P.h1lo    = (ushort*)w;   w += al((size_t)P.N * 128 * 2);
  P.h2      = (ushort*)w;   w += al((size_t)P.N * 64 * 2);
  P.w1hi    = (ushort*)w;   w += al((size_t)128 * 128 * 2);
  P.w1lo    = (ushort*)w;   w += al((size_t)128 * 128 * 2);
  P.w2hi    = (ushort*)w;   w += al((size_t)128 * 64 * 2);
  P.w2lo    = (ushort*)w;   w += al((size_t)128 * 64 * 2);
  P.out = (float*)d_out;

  // Size the cooperative grid from the runtime's own occupancy calculation
  // (host-side queries; no stream interaction -> graph-capture safe).
  hipError_t err = hipErrorUnknown;
  int devId = 0, numCU = 0, maxBlk = 0;
  if (hipGetDevice(&devId) == hipSuccess &&
      hipDeviceGetAttribute(&numCU, hipDeviceAttributeMultiprocessorCount, devId) == hipSuccess &&
      hipOccupancyMaxActiveBlocksPerMultiprocessor(&maxBlk, (const void*)k_mega, 256, 0) == hipSuccess &&
      numCU > 0 && maxBlk > 0) {
    int grid = numCU * maxBlk;
    if (grid > 1024) grid = 1024;
    void* kargs[] = {(void*)&P};
    err = hipLaunchCooperativeKernel((const void*)k_mega, dim3(grid), dim3(256),
                                     kargs, 0, stream);
  }
  if (err != hipSuccess) {
    // Fallback: proven R7 7-dispatch path (identical phase bodies).
    k_f1<<<PB + 12, 256, 0, stream>>>(P);
    k_f2<<<P.NBK + P.GB, 256, 0, stream>>>(P);
    k_f3<<<PB, 256, 0, stream>>>(P);
    k_f4<<<P.NBK, 256, 0, stream>>>(P);
    k_f5<<<P.NAGG, 256, 0, stream>>>(P);
    k_f6<<<P.GB, 256, 0, stream>>>(P);
    k_f7<<<P.NAGG, 256, 0, stream>>>(P);
  }
}

// Round 10
// 173.775 us; speedup vs baseline: 3.5376x; 3.5376x over previous
//
#include <hip/hip_runtime.h>

// GCN encoder: 2x (dense transform -> symmetric-normalized neighbor aggregation)
// R3: bf16x3 split MFMA GEMMs (no fp32 MFMA on CDNA4), W pre-swizzled.
// R4: aggregation gather tables bf16 -> halved beyond-L2 gather traffic.
// R5 FAILED: cross-thread fence race in ticket scan -> OOB -> abort.
// R6/R7: race-free fusions + atomic-free bucketed CSR build; 175.5 us.
// R8 FAILED / R9 REGRESSED (614 us): cooperative mega-kernel. grid.sync() on
//     MI355X costs ~100 us (device-wide L2 flush across 8 non-coherent XCD
//     L2s + 1024-block spin); kernel boundaries do the same flush in ~10 us
//     via the command processor. Multi-dispatch wins on this chip.
// R10: revert to multi-dispatch; compress 7 -> 6 dispatches: the per-bucket
//     block scan (old p2) is folded into the scatter kernel (each block
//     computes its own prefix from raw cnt_mat, ~2 us aggregate), and the
//     scatter kernel publishes bases[] so the CSR kernel skips its re-scan.

typedef __attribute__((ext_vector_type(8))) short short8;
typedef __attribute__((ext_vector_type(4))) float float4v;

constexpr int PB = 128;  // partition blocks (histogram/scatter chunks)

static __device__ __forceinline__ ushort f2bf(float f) {
  union { float f; unsigned u; } c; c.f = f;
  unsigned u = c.u;
  return (ushort)((u + 0x7fffu + ((u >> 16) & 1u)) >> 16);  // RNE
}
static __device__ __forceinline__ float bf2f(ushort h) {
  union { unsigned u; float f; } c; c.u = ((unsigned)h) << 16;
  return c.f;
}
static __device__ __forceinline__ float bfhi(unsigned packed) {
  union { unsigned u; float f; } c; c.u = packed & 0xffff0000u;
  return c.f;
}
static __device__ __forceinline__ float bflo(unsigned packed) {
  union { unsigned u; float f; } c; c.u = packed << 16;
  return c.f;
}

struct MegaParams {
  const float* x;
  const int* src;
  const int* dst;
  const float* W1;
  const float* b1;
  const float* W2;
  const float* b2;
  int N, E, NBK, EPB, GB, NAGG;
  int* cnt_mat;
  int* bases;      // [NBK+1] bucket base offsets (published by scatter kernel)
  unsigned* part;
  int* row_ptr;
  float* dinv;
  int* col;
  ushort* h;
  ushort* h1hi;
  ushort* h1lo;
  ushort* h2;
  ushort* w1hi;
  ushort* w1lo;
  ushort* w2hi;
  ushort* w2lo;
  float* out;
};

// W swizzle: one 16x32 B-fragment tile (64 lanes).
// Layout [ktile][ntile][lane][j]: B[k=(lane>>4)*8+j][n=lane&15]
static __device__ __forceinline__ void wswz_tile(const float* __restrict__ W,
                                                 ushort* __restrict__ whi,
                                                 ushort* __restrict__ wlo,
                                                 int M, int tile, int lane) {
  int ntiles = M >> 4;
  int kt = tile / ntiles, nt = tile % ntiles;
  int colg = nt * 16 + (lane & 15);
  int krow = kt * 32 + (lane >> 4) * 8;
  size_t o = ((size_t)tile * 64 + lane) * 8;
#pragma unroll
  for (int j = 0; j < 8; j++) {
    float v = W[(size_t)(krow + j) * M + colg];
    ushort h = f2bf(v);
    whi[o + j] = h;
    wlo[o + j] = f2bf(v - bf2f(h));
  }
}

// ---- K1: bucket histogram (bid<PB) + W swizzles (bid in [PB,PB+12)) ------
__global__ __launch_bounds__(256) void k_g1(MegaParams P) {
  __shared__ int hist[512];
  int bid = blockIdx.x, t = threadIdx.x;
  if (bid >= PB) {
    int tile = (bid - PB) * 4 + (t >> 6);
    int lane = t & 63;
    if (tile < 32) wswz_tile(P.W1, P.w1hi, P.w1lo, 128, tile, lane);
    else           wswz_tile(P.W2, P.w2hi, P.w2lo, 64, tile - 32, lane);
    return;
  }
  for (int k = t; k < P.NBK; k += 256) hist[k] = 0;
  __syncthreads();
  int start = bid * P.EPB;
  int stop = min(P.E, start + P.EPB);
  for (int e = start + t * 4; e < stop; e += 1024) {
    if (e + 4 <= stop) {
      int4 d = *(const int4*)(P.dst + e);
      atomicAdd(&hist[d.x >> 7], 1);
      atomicAdd(&hist[d.y >> 7], 1);
      atomicAdd(&hist[d.z >> 7], 1);
      atomicAdd(&hist[d.w >> 7], 1);
    } else {
      for (int j = e; j < stop; j++) atomicAdd(&hist[P.dst[j] >> 7], 1);
    }
  }
  __syncthreads();
  for (int k = t; k < P.NBK; k += 256) P.cnt_mat[k * PB + bid] = hist[k];
}

// ---- gemm1 block: C[64 rows, 128] = A @ W1, fp32 A split to bf16 hi/lo ----
static __device__ void gemm1_block(int gb, const MegaParams& P) {
  constexpr int K = 128, M = 128, NT = M / 16;
  int t = threadIdx.x;
  int lane = t & 63;
  int wv = t >> 6;
  int quad = lane >> 4, lo16 = lane & 15;
  int rowbase = gb * 64 + wv * 16;
  int arow = rowbase + lo16;
  bool arow_ok = arow < P.N;
  float4v acc[NT];
#pragma unroll
  for (int nt = 0; nt < NT; nt++) acc[nt] = (float4v){0.f, 0.f, 0.f, 0.f};
  for (int kt = 0; kt < 4; kt++) {
    short8 ahi, alo;
    float av[8];
    if (arow_ok) {
      const float* ap = P.x + (size_t)arow * K + kt * 32 + quad * 8;
      float4 a0 = *(const float4*)ap;
      float4 a1 = *(const float4*)(ap + 4);
      av[0] = a0.x; av[1] = a0.y; av[2] = a0.z; av[3] = a0.w;
      av[4] = a1.x; av[5] = a1.y; av[6] = a1.z; av[7] = a1.w;
    } else {
#pragma unroll
      for (int j = 0; j < 8; j++) av[j] = 0.f;
    }
#pragma unroll
    for (int j = 0; j < 8; j++) {
      ushort hh = f2bf(av[j]);
      ahi[j] = (short)hh;
      alo[j] = (short)f2bf(av[j] - bf2f(hh));
    }
    const ushort* ph = P.w1hi + ((size_t)(kt * NT) * 64 + lane) * 8;
    const ushort* pl = P.w1lo + ((size_t)(kt * NT) * 64 + lane) * 8;
#pragma unroll
    for (int nt = 0; nt < NT; nt++) {
      short8 bhi = *(const short8*)(ph + nt * 512);
      short8 blo = *(const short8*)(pl + nt * 512);
      acc[nt] = __builtin_amdgcn_mfma_f32_16x16x32_bf16(ahi, bhi, acc[nt], 0, 0, 0);
      acc[nt] = __builtin_amdgcn_mfma_f32_16x16x32_bf16(alo, bhi, acc[nt], 0, 0, 0);
      acc[nt] = __builtin_amdgcn_mfma_f32_16x16x32_bf16(ahi, blo, acc[nt], 0, 0, 0);
    }
  }
  // D layout (m89-verified): col = lane&15, row = quad*4 + reg
#pragma unroll
  for (int nt = 0; nt < NT; nt++) {
#pragma unroll
    for (int r = 0; r < 4; r++) {
      int row = rowbase + quad * 4 + r;
      if (row < P.N) P.h[(size_t)row * M + nt * 16 + lo16] = f2bf(acc[nt][r]);
    }
  }
}

// ---- K2: partition scatter w/ self-computed prefixes (bid<PB) || gemm1 ----
// Each scatter block derives, from RAW cnt_mat: per-bucket totals (full row
// sum), its own within-bucket prefix (sum of cols < bid), and the bucket base
// (LDS scan of totals). Block 0 publishes bases[] for K3.
__global__ __launch_bounds__(256) void k_g2(MegaParams P) {
  __shared__ int buf[256];
  __shared__ int base[512];
  __shared__ int tot[512];
  __shared__ int cur[512];
  int bid = blockIdx.x, t = threadIdx.x;
  if (bid >= PB) {
    gemm1_block(bid - PB, P);
    return;
  }
  // totals + own prefix from raw counts
  for (int k = t; k < P.NBK; k += 256) {
    const int* row = P.cnt_mat + (size_t)k * PB;
    int pre = 0, s = 0;
    for (int b = 0; b < PB; b++) {
      int c = row[b];
      s += c;
      if (b < bid) pre += c;
    }
    tot[k] = s;
    cur[k] = pre;  // within-bucket offset of this block's chunk
  }
  __syncthreads();
  // exclusive scan of tot -> base (base[idx>=NBK] = E)
  {
    int carry = 0;
    for (int b0 = 0; b0 < 512; b0 += 256) {
      int idx = b0 + t;
      int v = (idx < P.NBK) ? tot[idx] : 0;
      buf[t] = v;
      __syncthreads();
      for (int off = 1; off < 256; off <<= 1) {
        int add = (t >= off) ? buf[t - off] : 0;
        __syncthreads();
        buf[t] += add;
        __syncthreads();
      }
      base[idx] = carry + buf[t] - v;
      carry += buf[255];
      __syncthreads();
    }
  }
  for (int k = t; k < P.NBK; k += 256) cur[k] += base[k];
  if (bid == 0)
    for (int k = t; k <= P.NBK; k += 256) P.bases[k] = base[k];
  __syncthreads();
  int start = bid * P.EPB, stop = min(P.E, start + P.EPB);
  for (int e = start + t * 4; e < stop; e += 1024) {
    if (e + 4 <= stop) {
      int4 s = *(const int4*)(P.src + e);
      int4 d = *(const int4*)(P.dst + e);
      int p;
      p = atomicAdd(&cur[d.x >> 7], 1); P.part[p] = (unsigned)s.x | ((unsigned)(d.x & 127) << 25);
      p = atomicAdd(&cur[d.y >> 7], 1); P.part[p] = (unsigned)s.y | ((unsigned)(d.y & 127) << 25);
      p = atomicAdd(&cur[d.z >> 7], 1); P.part[p] = (unsigned)s.z | ((unsigned)(d.z & 127) << 25);
      p = atomicAdd(&cur[d.w >> 7], 1); P.part[p] = (unsigned)s.w | ((unsigned)(d.w & 127) << 25);
    } else {
      for (int j = e; j < stop; j++) {
        int p2 = atomicAdd(&cur[P.dst[j] >> 7], 1);
        P.part[p2] = (unsigned)P.src[j] | ((unsigned)(P.dst[j] & 127) << 25);
      }
    }
  }
}

// ---- K3: per-bucket local CSR (LDS count/scan/place); bases from K2 -------
__global__ __launch_bounds__(256) void k_g3(MegaParams P) {
  __shared__ int buf[256];
  __shared__ int cnt[128];
  __shared__ int cur[128];
  int bid = blockIdx.x, t = threadIdx.x;
  int beg = P.bases[bid], end = P.bases[bid + 1];
  if (t < 128) cnt[t] = 0;
  __syncthreads();
  for (int e = beg + t; e < end; e += 256) atomicAdd(&cnt[P.part[e] >> 25], 1);
  __syncthreads();
  int v = (t < 128) ? cnt[t] : 0;
  buf[t] = v;
  __syncthreads();
#pragma unroll
  for (int off = 1; off < 256; off <<= 1) {
    int add = (t >= off) ? buf[t - off] : 0;
    __syncthreads();
    buf[t] += add;
    __syncthreads();
  }
  if (t < 128) {
    int excl = buf[t] - v;
    cur[t] = beg + excl;
    int node = bid * 128 + t;
    if (node < P.N) {
      P.row_ptr[node] = beg + excl;
      P.dinv[node] = rsqrtf((float)(v + 1));  // +1 self loop
    }
  }
  if (bid == 0 && t == 0) P.row_ptr[P.N] = P.E;
  __syncthreads();
  for (int e = beg + t; e < end; e += 256) {
    unsigned p = P.part[e];
    int pos = atomicAdd(&cur[p >> 25], 1);
    P.col[pos] = (int)(p & 0x01FFFFFFu);
  }
}

// ---- aggregation: one wave per node, channels across lanes ----
template <int C, bool RELU, bool SPLIT>
static __device__ void agg_block(int vb, const MegaParams& P,
                                 const ushort* __restrict__ Hb,
                                 const float* __restrict__ bias,
                                 float* __restrict__ out,
                                 ushort* __restrict__ outhi,
                                 ushort* __restrict__ outlo) {
  constexpr int VPL = C / 64;  // 2 (C=128) or 1 (C=64)
  int lane = threadIdx.x & 63;
  int v = vb * 4 + (threadIdx.x >> 6);
  if (v >= P.N) return;
  float dv = P.dinv[v];
  float acc0 = 0.f, acc1 = 0.f;
  auto loadp = [&](int s) -> unsigned {
    if (VPL == 2) return *(const unsigned*)(Hb + (size_t)s * C + lane * 2);
    else          return (unsigned)Hb[(size_t)s * C + lane];
  };
  {
    unsigned u = loadp(v);  // self loop (weight dv)
    if (VPL == 2) { acc0 = dv * bflo(u); acc1 = dv * bfhi(u); }
    else          { acc0 = dv * bf2f((ushort)u); }
  }
  int beg = P.row_ptr[v], end = P.row_ptr[v + 1];
  for (int base = beg; base < end; base += 64) {
    int m = end - base;
    if (m > 64) m = 64;
    int sl = 0;
    float wl = 0.f;
    if (lane < m) {
      sl = P.col[base + lane];
      wl = P.dinv[sl];
    }
    int j = 0;
    for (; j + 8 <= m; j += 8) {
      int s[8]; float wq[8]; unsigned u[8];
#pragma unroll
      for (int q = 0; q < 8; q++) { s[q] = __shfl(sl, j + q); wq[q] = __shfl(wl, j + q); }
#pragma unroll
      for (int q = 0; q < 8; q++) u[q] = loadp(s[q]);
#pragma unroll
      for (int q = 0; q < 8; q++) {
        if (VPL == 2) {
          acc0 = fmaf(wq[q], bflo(u[q]), acc0);
          acc1 = fmaf(wq[q], bfhi(u[q]), acc1);
        } else {
          acc0 = fmaf(wq[q], bf2f((ushort)u[q]), acc0);
        }
      }
    }
    for (; j + 4 <= m; j += 4) {
      int s[4]; float wq[4]; unsigned u[4];
#pragma unroll
      for (int q = 0; q < 4; q++) { s[q] = __shfl(sl, j + q); wq[q] = __shfl(wl, j + q); }
#pragma unroll
      for (int q = 0; q < 4; q++) u[q] = loadp(s[q]);
#pragma unroll
      for (int q = 0; q < 4; q++) {
        if (VPL == 2) {
          acc0 = fmaf(wq[q], bflo(u[q]), acc0);
          acc1 = fmaf(wq[q], bfhi(u[q]), acc1);
        } else {
          acc0 = fmaf(wq[q], bf2f((ushort)u[q]), acc0);
        }
      }
    }
    for (; j < m; j++) {
      int s = __shfl(sl, j);
      float wv = __shfl(wl, j);
      unsigned u = loadp(s);
      if (VPL == 2) {
        acc0 = fmaf(wv, bflo(u), acc0);
        acc1 = fmaf(wv, bfhi(u), acc1);
      } else {
        acc0 = fmaf(wv, bf2f((ushort)u), acc0);
      }
    }
  }
  float r0 = fmaf(dv, acc0, bias[lane * VPL + 0]);
  if (RELU) r0 = fmaxf(r0, 0.f);
  if (VPL == 2) {
    float r1 = fmaf(dv, acc1, bias[lane * VPL + 1]);
    if (RELU) r1 = fmaxf(r1, 0.f);
    if (SPLIT) {
      ushort h0 = f2bf(r0), h1 = f2bf(r1);
      ushort l0 = f2bf(r0 - bf2f(h0)), l1 = f2bf(r1 - bf2f(h1));
      ((unsigned*)outhi)[(size_t)v * (C / 2) + lane] = (unsigned)h0 | ((unsigned)h1 << 16);
      ((unsigned*)outlo)[(size_t)v * (C / 2) + lane] = (unsigned)l0 | ((unsigned)l1 << 16);
    } else {
      *(float2*)&out[(size_t)v * C + lane * 2] = make_float2(r0, r1);
    }
  } else {
    out[(size_t)v * C + lane] = r0;
  }
}

// ---- K5: gemm2 block: PRESPLIT bf16 hi/lo in, bf16 out, M=64 ----
__global__ __launch_bounds__(256) void k_g5(MegaParams P) {
  constexpr int K = 128, M = 64, NT = M / 16;
  int t = threadIdx.x;
  int lane = t & 63;
  int wv = t >> 6;
  int quad = lane >> 4, lo16 = lane & 15;
  int rowbase = blockIdx.x * 64 + wv * 16;
  int arow = rowbase + lo16;
  bool arow_ok = arow < P.N;
  float4v acc[NT];
#pragma unroll
  for (int nt = 0; nt < NT; nt++) acc[nt] = (float4v){0.f, 0.f, 0.f, 0.f};
  for (int kt = 0; kt < 4; kt++) {
    short8 ahi, alo;
    if (arow_ok) {
      size_t ao = (size_t)arow * K + kt * 32 + quad * 8;
      ahi = *(const short8*)(P.h1hi + ao);
      alo = *(const short8*)(P.h1lo + ao);
    } else {
      ahi = (short8)0; alo = (short8)0;
    }
    const ushort* ph = P.w2hi + ((size_t)(kt * NT) * 64 + lane) * 8;
    const ushort* pl = P.w2lo + ((size_t)(kt * NT) * 64 + lane) * 8;
#pragma unroll
    for (int nt = 0; nt < NT; nt++) {
      short8 bhi = *(const short8*)(ph + nt * 512);
      short8 blo = *(const short8*)(pl + nt * 512);
      acc[nt] = __builtin_amdgcn_mfma_f32_16x16x32_bf16(ahi, bhi, acc[nt], 0, 0, 0);
      acc[nt] = __builtin_amdgcn_mfma_f32_16x16x32_bf16(alo, bhi, acc[nt], 0, 0, 0);
      acc[nt] = __builtin_amdgcn_mfma_f32_16x16x32_bf16(ahi, blo, acc[nt], 0, 0, 0);
    }
  }
#pragma unroll
  for (int nt = 0; nt < NT; nt++) {
#pragma unroll
    for (int r = 0; r < 4; r++) {
      int row = rowbase + quad * 4 + r;
      if (row < P.N) P.h2[(size_t)row * M + nt * 16 + lo16] = f2bf(acc[nt][r]);
    }
  }
}

__global__ __launch_bounds__(256) void k_g4(MegaParams P) {
  agg_block<128, true, true>(blockIdx.x, P, P.h, P.b1, nullptr, P.h1hi, P.h1lo);
}
__global__ __launch_bounds__(256) void k_g6(MegaParams P) {
  agg_block<64, false, false>(blockIdx.x, P, P.h2, P.b2, P.out, nullptr, nullptr);
}

extern "C" void kernel_launch(void* const* d_in, const int* in_sizes, int n_in,
                              void* d_out, int out_size, void* d_ws, size_t ws_size,
                              hipStream_t stream) {
  MegaParams P;
  P.x  = (const float*)d_in[0];
  const int* ei = (const int*)d_in[1];
  P.W1 = (const float*)d_in[2];
  P.b1 = (const float*)d_in[3];
  P.W2 = (const float*)d_in[4];
  P.b2 = (const float*)d_in[5];
  P.N = in_sizes[0] / 128;
  P.E = in_sizes[1] / 2;
  P.src = ei;
  P.dst = ei + P.E;
  P.NBK = (P.N + 127) / 128;                   // 391; must be <= 511
  P.EPB = ((P.E + PB - 1) / PB + 3) & ~3;      // edges per partition block, x4
  P.GB = (P.N + 63) / 64;                      // 782
  P.NAGG = (P.N + 3) / 4;                      // 12500

  auto al = [](size_t v) { return (v + 255) & ~(size_t)255; };
  char* w = (char*)d_ws;
  P.cnt_mat = (int*)w;      w += al((size_t)P.NBK * PB * 4);
  P.bases   = (int*)w;      w += al((size_t)(P.NBK + 1) * 4);
  P.part    = (unsigned*)w; w += al((size_t)P.E * 4);
  P.row_ptr = (int*)w;      w += al((size_t)(P.N + 1) * 4);
  P.dinv    = (float*)w;    w += al((size_t)P.N * 4);
  P.col     = (int*)w;      w += al((size_t)P.E * 4);
  P.h       = (ushort*)w;   w += al((size_t)P.N * 128 * 2);
  P.h1hi    = (ushort*)w;   w += al((size_t)P.N * 128 * 2);
  P.h1lo    = (ushort*)w;   w += al((size_t)P.N * 128 * 2);
  P.h2      = (ushort*)w;   w += al((size_t)P.N * 64 * 2);
  P.w1hi    = (ushort*)w;   w += al((size_t)128 * 128 * 2);
  P.w1lo    = (ushort*)w;   w += al((size_t)128 * 128 * 2);
  P.w2hi    = (ushort*)w;   w += al((size_t)128 * 64 * 2);
  P.w2lo    = (ushort*)w;   w += al((size_t)128 * 64 * 2);
  P.out = (float*)d_out;

  k_g1<<<PB + 12, 256, 0, stream>>>(P);
  k_g2<<<PB + P.GB, 256, 0, stream>>>(P);
  k_g3<<<P.NBK, 256, 0, stream>>>(P);
  k_g4<<<P.NAGG, 256, 0, stream>>>(P);
  k_g5<<<P.GB, 256, 0, stream>>>(P);
  k_g6<<<P.NAGG, 256, 0, stream>>>(P);
}